// Round 11
// baseline (394.006 us; speedup 1.0000x reference)
//
#include <hip/hip_runtime.h>
#include <hip/hip_bf16.h>

typedef __attribute__((ext_vector_type(8))) short bf16x8;
typedef __attribute__((ext_vector_type(4))) float f32x4;
typedef __attribute__((ext_vector_type(4))) unsigned short u16x4;
typedef __hip_bfloat16 bf16;

#define DEV __device__ __forceinline__
DEV float bf2f(bf16 v) { return __bfloat162float(v); }
DEV bf16  f2bf(float v) { return __float2bfloat16(v); }
DEV float sigmoidf_(float x) { return __builtin_amdgcn_rcpf(1.0f + __expf(-x)); }

typedef const __attribute__((address_space(1))) void* gptr_t;
typedef __attribute__((address_space(3))) void* lptr_t;

template<int N> DEV void waitcnt_vm() {
    if constexpr (N == 0) asm volatile("s_waitcnt vmcnt(0)" ::: "memory");
    else if constexpr (N == 2) asm volatile("s_waitcnt vmcnt(2)" ::: "memory");
    else if constexpr (N == 3) asm volatile("s_waitcnt vmcnt(3)" ::: "memory");
    else asm volatile("s_waitcnt vmcnt(4)" ::: "memory");
}

// ---------------------------------------------------------------------------
// bf16 MFMA GEMM (R8-verified): C = act(A @ W^T + bias)
// ACT: 0 none, 1 relu, 2 softplus, 3 silu. OUTBF: 1 bf16, 0 f32.
// ---------------------------------------------------------------------------
template<int BM, int BN, int ACT, int OUTBF>
__global__ __launch_bounds__(256)
void gemm_mfma(const bf16* __restrict__ A, int lda,
               const bf16* __restrict__ W, int ldw,
               const float* __restrict__ bias,
               void* __restrict__ Cp, int ldc, int K)
{
    constexpr int BK = 32;
    constexpr int WMS = BM / 2, WNS = BN / 2;
    constexpr int FM = WMS / 16, FN = WNS / 16;
    constexpr int AITER = (BM * BK) / (256 * 8);
    constexpr int BITER = (BN * BK) / (256 * 8);
    constexpr int NLD = AITER + BITER;
    constexpr int BUFB = (BM + BN) * BK * 2;

    __shared__ __align__(16) char smem[2 * BUFB];

    const int tid = threadIdx.x;
    const int lane = tid & 63;
    const int wid = tid >> 6;
    const int wm = wid >> 1, wn = wid & 1;
    const long m0 = (long)blockIdx.y * BM;
    const long n0 = (long)blockIdx.x * BN;

    f32x4 acc[FM][FN] = {};

    long aoff[AITER];
#pragma unroll
    for (int it = 0; it < AITER; ++it) {
        int q = it * 256 + tid;
        int r = q >> 2;
        aoff[it] = (long)(m0 + r) * lda * 2 + (((q & 3) * 16) ^ ((r & 3) << 4));
    }
    long boff[BITER];
#pragma unroll
    for (int it = 0; it < BITER; ++it) {
        int q = it * 256 + tid;
        int r = q >> 2;
        boff[it] = (long)(n0 + r) * ldw * 2 + (((q & 3) * 16) ^ ((r & 3) << 4));
    }

    const char* Ac = (const char*)A;
    const char* Wc = (const char*)W;

#pragma unroll
    for (int it = 0; it < AITER; ++it)
        __builtin_amdgcn_global_load_lds((gptr_t)(Ac + aoff[it]),
            (lptr_t)(smem + (it * 256 + wid * 64) * 16), 16, 0, 0);
#pragma unroll
    for (int it = 0; it < BITER; ++it)
        __builtin_amdgcn_global_load_lds((gptr_t)(Wc + boff[it]),
            (lptr_t)(smem + BM * BK * 2 + (it * 256 + wid * 64) * 16), 16, 0, 0);

    const int NK = K / BK;
    const int fr = lane & 15, fq = lane >> 4;
    const int swz = (fr & 3) << 4;
    int cur = 0;

    for (int ks = 0; ks < NK; ++ks) {
        if (ks + 1 < NK) {
            const long k2 = (long)(ks + 1) * BK * 2;
            char* dst = smem + (cur ^ 1) * BUFB;
#pragma unroll
            for (int it = 0; it < AITER; ++it)
                __builtin_amdgcn_global_load_lds((gptr_t)(Ac + aoff[it] + k2),
                    (lptr_t)(dst + (it * 256 + wid * 64) * 16), 16, 0, 0);
#pragma unroll
            for (int it = 0; it < BITER; ++it)
                __builtin_amdgcn_global_load_lds((gptr_t)(Wc + boff[it] + k2),
                    (lptr_t)(dst + BM * BK * 2 + (it * 256 + wid * 64) * 16), 16, 0, 0);
            waitcnt_vm<NLD>();
        } else {
            waitcnt_vm<0>();
        }
        __builtin_amdgcn_s_barrier();
        __builtin_amdgcn_sched_barrier(0);

        const char* base = smem + cur * BUFB;
        bf16x8 av[FM], bv[FN];
#pragma unroll
        for (int fm = 0; fm < FM; ++fm) {
            int ra = wm * WMS + fm * 16 + fr;
            av[fm] = *(const bf16x8*)(base + ra * 64 + ((fq * 16) ^ swz));
        }
#pragma unroll
        for (int fn = 0; fn < FN; ++fn) {
            int rb = wn * WNS + fn * 16 + fr;
            bv[fn] = *(const bf16x8*)(base + BM * BK * 2 + rb * 64 + ((fq * 16) ^ swz));
        }
#pragma unroll
        for (int fm = 0; fm < FM; ++fm)
#pragma unroll
            for (int fn = 0; fn < FN; ++fn)
                acc[fm][fn] = __builtin_amdgcn_mfma_f32_16x16x32_bf16(
                    av[fm], bv[fn], acc[fm][fn], 0, 0, 0);

        asm volatile("s_waitcnt lgkmcnt(0)" ::: "memory");
        __builtin_amdgcn_sched_barrier(0);
        __builtin_amdgcn_s_barrier();
        cur ^= 1;
    }

    float bcol[FN];
#pragma unroll
    for (int fn = 0; fn < FN; ++fn)
        bcol[fn] = bias ? bias[n0 + wn * WNS + fn * 16 + fr] : 0.0f;

    if constexpr (OUTBF) {
        constexpr int CST = BN + 8;
        bf16* ct = (bf16*)smem;
        for (int mh = 0; mh < BM / 64; ++mh) {
            __syncthreads();
            if (BM == 64 || wm == mh) {
#pragma unroll
                for (int fm = 0; fm < FM; ++fm) {
                    int lr0 = (BM == 64 ? wm * WMS : 0) + fm * 16 + fq * 4;
#pragma unroll
                    for (int fn = 0; fn < FN; ++fn) {
                        int lc = wn * WNS + fn * 16 + fr;
#pragma unroll
                        for (int r = 0; r < 4; ++r) {
                            float v = acc[fm][fn][r] + bcol[fn];
                            if (ACT == 1) v = fmaxf(v, 0.0f);
                            else if (ACT == 2)
                                v = fmaxf(v, 0.0f) + __logf(1.0f + __expf(-fabsf(v)));
                            else if (ACT == 3)
                                v = v * sigmoidf_(v);
                            ct[(lr0 + r) * CST + lc] = f2bf(v);
                        }
                    }
                }
            }
            __syncthreads();
            constexpr int GPR = BN / 8;
#pragma unroll
            for (int it = 0; it < (64 * GPR) / 256; ++it) {
                int idx = it * 256 + tid;
                int row = idx / GPR, cg = idx % GPR;
                bf16x8 v8 = *(const bf16x8*)&ct[row * CST + cg * 8];
                *(bf16x8*)((bf16*)Cp + (size_t)(m0 + mh * 64 + row) * ldc
                           + n0 + cg * 8) = v8;
            }
        }
    } else {
#pragma unroll
        for (int fn = 0; fn < FN; ++fn) {
            long col = n0 + wn * WNS + fn * 16 + fr;
#pragma unroll
            for (int fm = 0; fm < FM; ++fm) {
                long row0 = m0 + wm * WMS + fm * 16 + fq * 4;
#pragma unroll
                for (int r = 0; r < 4; ++r) {
                    float v = acc[fm][fn][r] + bcol[fn];
                    if (ACT == 1) v = fmaxf(v, 0.0f);
                    ((float*)Cp)[(size_t)(row0 + r) * ldc + col] = v;
                }
            }
        }
    }
}

// ---------------------------------------------------------------------------
struct CastJobs {
    const float* src[9];
    bf16* dst[9];
    int n[9];
};

__global__ __launch_bounds__(256)
void cast_bf16_kernel(CastJobs J)
{
    const int seg = blockIdx.y;
    const f32x4* s = (const f32x4*)J.src[seg];
    u16x4* d = (u16x4*)J.dst[seg];
    const int n4 = J.n[seg] >> 2;
    for (int i = blockIdx.x * 256 + threadIdx.x; i < n4; i += gridDim.x * 256) {
        f32x4 v = s[i];
        u16x4 o;
#pragma unroll
        for (int j = 0; j < 4; ++j) {
            bf16 b = f2bf(v[j]);
            o[j] = *(unsigned short*)&b;
        }
        d[i] = o;
    }
}

#define DSTATE 16
#define CHUNK 32      // scan chunk (NC = 64)

// ---------------------------------------------------------------------------
// Depthwise causal conv (k=4) + bias + silu. bf16 in/out, f32 math.
// ---------------------------------------------------------------------------
__global__ __launch_bounds__(256)
void conv_silu_kernel(const bf16* __restrict__ xmr, const float* __restrict__ cw,
                      const float* __restrict__ cb, bf16* __restrict__ xms, int L)
{
    const int NCc = L / 32;
    const int c = blockIdx.x % NCc;
    const int b = blockIdx.x / NCc;
    const int d = blockIdx.y * 256 + threadIdx.x;

    const float w0 = cw[d * 4 + 0], w1 = cw[d * 4 + 1];
    const float w2 = cw[d * 4 + 2], w3 = cw[d * 4 + 3];
    const float bb = cb[d];

    const int t0 = c * 32;
    float x0 = 0.f, x1 = 0.f, x2 = 0.f;
    if (t0 >= 3) {
        x0 = bf2f(xmr[(size_t)(b * L + t0 - 3) * 1024 + d]);
        x1 = bf2f(xmr[(size_t)(b * L + t0 - 2) * 1024 + d]);
        x2 = bf2f(xmr[(size_t)(b * L + t0 - 1) * 1024 + d]);
    }
    for (int t = t0; t < t0 + 32; ++t) {
        float x3 = bf2f(xmr[(size_t)(b * L + t) * 1024 + d]);
        float v = fmaf(w0, x0, fmaf(w1, x1, fmaf(w2, x2, fmaf(w3, x3, bb))));
        xms[(size_t)(b * L + t) * 1024 + d] = f2bf(v * sigmoidf_(v));
        x0 = x1; x1 = x2; x2 = x3;
    }
}

// ---------------------------------------------------------------------------
// A helper: detect A_s == -(s+1) (A_log = log(arange(1..16)) broadcast).
// ---------------------------------------------------------------------------
DEV bool load_A(const float* __restrict__ A_log, int d, float* As_)
{
    bool fastA = true;
#pragma unroll
    for (int s = 0; s < DSTATE; ++s) {
        As_[s] = -__expf(A_log[(size_t)d * DSTATE + s]);
        fastA = fastA && (fabsf(As_[s] + (float)(s + 1)) <= 1e-4f * (s + 1));
    }
    return fastA;
}

// a[s] = r^(s+1), 15 muls, depth 5.
DEV void powa(float r, float* a)
{
    float r2 = r * r;
    float r3 = r2 * r;
    float r4 = r2 * r2;
    float r8 = r4 * r4;
    a[0] = r;       a[1] = r2;      a[2] = r3;      a[3] = r4;
    a[4] = r4 * r;  a[5] = r4 * r2; a[6] = r4 * r3; a[7] = r8;
    a[8] = r8 * r;  a[9] = r8 * r2; a[10] = r8 * r3; a[11] = r8 * r4;
    a[12] = a[11] * r; a[13] = a[11] * r2; a[14] = a[11] * r3; a[15] = r8 * r8;
}

// ---------------------------------------------------------------------------
// Scan pass 1: local scan; writes chunk-end S, P, AND ylocal in place over
// xms. B/C interleaved in LDS ([t][2s]/[2s+1]) for b64/b128 merged reads;
// t-loop unrolled x8; 4-way yl chains.
// ---------------------------------------------------------------------------
__global__ __launch_bounds__(256)
void scan_pass1(const bf16* __restrict__ delta, bf16* xms /* in: xm, out: ylocal */,
                const bf16* __restrict__ dblb, const float* __restrict__ A_log,
                const float* __restrict__ Dp,
                bf16* __restrict__ P, bf16* __restrict__ S, int L)
{
    const int NC = L / CHUNK;
    const int c = blockIdx.x % NC;
    const int b = blockIdx.x / NC;
    const int d = blockIdx.y * 256 + threadIdx.x;

    __shared__ float BC[CHUNK][2 * DSTATE];    // [t][2s]=B, [2s+1]=C
#pragma unroll
    for (int it = 0; it < CHUNK * DSTATE / 256; ++it) {
        int idx = threadIdx.x + it * 256;
        int t = idx >> 4, s = idx & 15;
        size_t base = (size_t)(b * L + c * CHUNK + t) * 64;
        BC[t][2 * s]     = bf2f(dblb[base + 32 + s]);
        BC[t][2 * s + 1] = bf2f(dblb[base + 48 + s]);
    }
    __syncthreads();

    float As_[DSTATE];
    const bool fastA = load_A(A_log, d, As_);
    const float Dd = Dp[d];

    float h[DSTATE];
#pragma unroll
    for (int s = 0; s < DSTATE; ++s) h[s] = 0.f;

    const size_t rb = (size_t)(b * L + c * CHUNK);

    if (fastA) {
        float sumd = 0.f;
#pragma unroll 8
        for (int t = 0; t < CHUNK; ++t) {
            size_t g = (rb + t) * 1024 + d;
            float de = bf2f(delta[g]);
            float x  = bf2f(xms[g]);
            float dx = de * x;
            float r = __expf(-de);
            float a[DSTATE];
            powa(r, a);
            sumd += de;
            float y0 = x * Dd, y1 = 0.f, y2 = 0.f, y3 = 0.f;
#pragma unroll
            for (int s = 0; s < DSTATE; s += 4) {
                h[s]   = fmaf(a[s],   h[s],   dx * BC[t][2*s]);
                y0 = fmaf(h[s],   BC[t][2*s+1], y0);
                h[s+1] = fmaf(a[s+1], h[s+1], dx * BC[t][2*s+2]);
                y1 = fmaf(h[s+1], BC[t][2*s+3], y1);
                h[s+2] = fmaf(a[s+2], h[s+2], dx * BC[t][2*s+4]);
                y2 = fmaf(h[s+2], BC[t][2*s+5], y2);
                h[s+3] = fmaf(a[s+3], h[s+3], dx * BC[t][2*s+6]);
                y3 = fmaf(h[s+3], BC[t][2*s+7], y3);
            }
            xms[g] = f2bf((y0 + y1) + (y2 + y3));
        }
        float Rc = __expf(-sumd);
        float pa[DSTATE];
        powa(Rc, pa);
#pragma unroll
        for (int s = 0; s < DSTATE; ++s) {
            size_t o = ((size_t)(b * NC + c) * DSTATE + s) * 1024 + d;
            P[o] = f2bf(pa[s]);
            S[o] = f2bf(h[s]);
        }
    } else {
        float p[DSTATE];
#pragma unroll
        for (int s = 0; s < DSTATE; ++s) p[s] = 1.f;
        for (int t = 0; t < CHUNK; ++t) {
            size_t g = (rb + t) * 1024 + d;
            float de = bf2f(delta[g]);
            float x  = bf2f(xms[g]);
            float dx = de * x;
            float yl = x * Dd;
#pragma unroll
            for (int s = 0; s < DSTATE; ++s) {
                float dA = __expf(de * As_[s]);
                h[s] = fmaf(dA, h[s], dx * BC[t][2*s]);
                p[s] *= dA;
                yl = fmaf(h[s], BC[t][2*s+1], yl);
            }
            xms[g] = f2bf(yl);
        }
#pragma unroll
        for (int s = 0; s < DSTATE; ++s) {
            size_t o = ((size_t)(b * NC + c) * DSTATE + s) * 1024 + d;
            P[o] = f2bf(p[s]);
            S[o] = f2bf(h[s]);
        }
    }
}

// ---------------------------------------------------------------------------
// Pass 2: serial combine over NC=64 chunks, 8-deep batched, Hinit over P.
// ---------------------------------------------------------------------------
__global__ __launch_bounds__(256)
void scan_pass2(const bf16* P, const bf16* __restrict__ S, bf16* Hinit, int NC)
{
    int g = blockIdx.x * 256 + threadIdx.x;
    int d = g & 1023;
    int s = (g >> 10) & 15;
    int b = g >> 14;
    const size_t cs = (size_t)DSTATE * 1024;
    size_t o = ((size_t)(b * NC) * DSTATE + s) * 1024 + d;
    float h = 0.f;
    for (int c0 = 0; c0 < NC; c0 += 8) {
        float pv[8], sv[8];
#pragma unroll
        for (int j = 0; j < 8; ++j) {
            pv[j] = bf2f(P[o + j * cs]);
            sv[j] = bf2f(S[o + j * cs]);
        }
#pragma unroll
        for (int j = 0; j < 8; ++j) {
            Hinit[o + j * cs] = f2bf(h);
            h = fmaf(pv[j], h, sv[j]);
        }
        o += 8 * cs;
    }
}

// ---------------------------------------------------------------------------
// Pass 3 (correction-only): dY holds delta on entry, final y*z on exit
// (same buffer — single pointer so the compiler can prove load/store
// disjointness across the unrolled window and batch loads).
// y_t = ylocal_t + sum_s C_t[s]*w_t[s]; w updated multiplicatively.
// ---------------------------------------------------------------------------
__global__ __launch_bounds__(256)
void scan_pass3(bf16* dY, const bf16* __restrict__ ylocal,
                const bf16* __restrict__ dblb, const float* __restrict__ A_log,
                const bf16* __restrict__ Hinit,
                const bf16* __restrict__ zs, int L)
{
    const int NC = L / CHUNK;
    const int c = blockIdx.x % NC;
    const int b = blockIdx.x / NC;
    const int d = blockIdx.y * 256 + threadIdx.x;

    __shared__ float Csh[CHUNK][DSTATE];
#pragma unroll
    for (int it = 0; it < CHUNK * DSTATE / 256; ++it) {
        int idx = threadIdx.x + it * 256;
        int t = idx >> 4, s = idx & 15;
        Csh[t][s] = bf2f(dblb[(size_t)(b * L + c * CHUNK + t) * 64 + 48 + s]);
    }
    __syncthreads();

    float As_[DSTATE];
    const bool fastA = load_A(A_log, d, As_);

    float w[DSTATE];
#pragma unroll
    for (int s = 0; s < DSTATE; ++s)
        w[s] = bf2f(Hinit[((size_t)(b * NC + c) * DSTATE + s) * 1024 + d]);

    const size_t rb = (size_t)(b * L + c * CHUNK);

    if (fastA) {
#pragma unroll 8
        for (int t = 0; t < CHUNK; ++t) {
            size_t g = (rb + t) * 1024 + d;
            float de = bf2f(dY[g]);
            float yl = bf2f(ylocal[g]);
            float z  = bf2f(zs[g]);
            float r = __expf(-de);
            float a[DSTATE];
            powa(r, a);
            float c0 = 0.f, c1 = 0.f, c2 = 0.f, c3 = 0.f;
#pragma unroll
            for (int s = 0; s < DSTATE; s += 4) {
                w[s] *= a[s];
                c0 = fmaf(w[s], Csh[t][s], c0);
                w[s+1] *= a[s+1];
                c1 = fmaf(w[s+1], Csh[t][s+1], c1);
                w[s+2] *= a[s+2];
                c2 = fmaf(w[s+2], Csh[t][s+2], c2);
                w[s+3] *= a[s+3];
                c3 = fmaf(w[s+3], Csh[t][s+3], c3);
            }
            dY[g] = f2bf((yl + (c0 + c1) + (c2 + c3)) * z);
        }
    } else {
        for (int t = 0; t < CHUNK; ++t) {
            size_t g = (rb + t) * 1024 + d;
            float de = bf2f(dY[g]);
            float yl = bf2f(ylocal[g]);
            float z  = bf2f(zs[g]);
            float c0 = 0.f, c1 = 0.f;
#pragma unroll
            for (int s = 0; s < DSTATE; s += 2) {
                w[s]   *= __expf(de * As_[s]);
                c0 = fmaf(w[s], Csh[t][s], c0);
                w[s+1] *= __expf(de * As_[s+1]);
                c1 = fmaf(w[s+1], Csh[t][s+1], c1);
            }
            dY[g] = f2bf((yl + c0 + c1) * z);
        }
    }
}

// ---------------------------------------------------------------------------

extern "C" void kernel_launch(void* const* d_in, const int* in_sizes, int n_in,
                              void* d_out, int out_size, void* d_ws, size_t ws_size,
                              hipStream_t stream)
{
    (void)in_sizes; (void)n_in; (void)out_size;

    const float* x         = (const float*)d_in[0];
    const float* enc_w1    = (const float*)d_in[1];
    const float* enc_b1    = (const float*)d_in[2];
    const float* enc_w2    = (const float*)d_in[3];
    const float* enc_b2    = (const float*)d_in[4];
    const float* in_proj_w = (const float*)d_in[5];
    const float* conv_w    = (const float*)d_in[6];
    const float* conv_b    = (const float*)d_in[7];
    const float* x_proj_w  = (const float*)d_in[8];
    const float* dt_proj_w = (const float*)d_in[9];
    const float* dt_proj_b = (const float*)d_in[10];
    const float* A_log     = (const float*)d_in[11];
    const float* D_param   = (const float*)d_in[12];
    const float* out_proj_w= (const float*)d_in[13];
    const float* dec_w1    = (const float*)d_in[14];
    const float* dec_b1    = (const float*)d_in[15];
    const float* dec_w2    = (const float*)d_in[16];
    const float* dec_b2    = (const float*)d_in[17];
    float* out = (float*)d_out;

    const int L = 2048, NC = L / CHUNK;   // NC = 64

    // ---- bf16 fixed region (weights + x) ----
    bf16* wb = (bf16*)d_ws;
    size_t off = 0;
    bf16* w_enc1 = wb + off; off += 16384;
    bf16* w_enc2 = wb + off; off += 131072;
    bf16* w_inpj = wb + off; off += 1048576;
    bf16* w_xprj = wb + off; off += 65536;
    bf16* w_dtpj = wb + off; off += 32768;
    bf16* w_outp = wb + off; off += 524288;
    bf16* w_dec1 = wb + off; off += 131072;
    bf16* w_dec2 = wb + off; off += 16384;
    bf16* xbf    = wb + off; off += 1048576;
    const size_t fixedB = off * 2;         // 6,029,312 B

    // per-row bytes: hbf(512)+ubf(1024)+slot3(2048)+zbf(2048)+xms(2048)
    //               +dblb(128)+Pb(1024)+Sb(1024) = 9856
    const size_t PER_ROW = 9856;
    int SPLIT = 8;
    if      (fixedB + (size_t)16384 * PER_ROW <= ws_size) SPLIT = 1;  // 167.5 MB
    else if (fixedB + (size_t) 8192 * PER_ROW <= ws_size) SPLIT = 2;  //  86.8 MB
    else if (fixedB + (size_t) 4096 * PER_ROW <= ws_size) SPLIT = 4;

    const int NB = 8 / SPLIT;
    const int MR = NB * L;

    char* pb = (char*)d_ws + fixedB;
    bf16* hbf   = (bf16*)pb;                     // MR x 256
    bf16* ubf   = hbf   + (size_t)MR * 256;      // MR x 512 (u, o)
    bf16* slot3 = ubf   + (size_t)MR * 512;      // MR x 1024 (xm_raw -> delta -> y)
    bf16* zbf   = slot3 + (size_t)MR * 1024;     // MR x 1024 (silu'd z)
    bf16* xms   = zbf   + (size_t)MR * 1024;     // MR x 1024 (xm_silu -> ylocal)
    bf16* dblb  = xms   + (size_t)MR * 1024;     // MR x 64
    bf16* Pb    = dblb  + (size_t)MR * 64;       // MR x 512 bf16 (-> Hinit)
    bf16* Sb    = Pb    + (size_t)MR * 512;      // MR x 512 bf16

    CastJobs J;
    J.src[0] = enc_w1;     J.dst[0] = w_enc1; J.n[0] = 16384;
    J.src[1] = enc_w2;     J.dst[1] = w_enc2; J.n[1] = 131072;
    J.src[2] = in_proj_w;  J.dst[2] = w_inpj; J.n[2] = 1048576;
    J.src[3] = x_proj_w;   J.dst[3] = w_xprj; J.n[3] = 65536;
    J.src[4] = dt_proj_w;  J.dst[4] = w_dtpj; J.n[4] = 32768;
    J.src[5] = out_proj_w; J.dst[5] = w_outp; J.n[5] = 524288;
    J.src[6] = dec_w1;     J.dst[6] = w_dec1; J.n[6] = 131072;
    J.src[7] = dec_w2;     J.dst[7] = w_dec2; J.n[7] = 16384;
    J.src[8] = x;          J.dst[8] = xbf;    J.n[8] = 1048576;
    cast_bf16_kernel<<<dim3(128, 9), 256, 0, stream>>>(J);

    dim3 blk(256);
    for (int p = 0; p < SPLIT; ++p) {
        const bf16* xp  = xbf + (size_t)p * MR * 64;
        float*     outp = out + (size_t)p * MR * 64;

        // enc1: relu(x @ enc_w1^T + b1) -> h (MR x 256), K=64
        gemm_mfma<64,128,1,1><<<dim3(2, MR/64), blk, 0, stream>>>(
            xp, 64, w_enc1, 64, enc_b1, hbf, 256, 64);
        // enc2: u = h @ enc_w2^T + b2 (MR x 512), K=256
        gemm_mfma<128,128,0,1><<<dim3(4, MR/128), blk, 0, stream>>>(
            hbf, 256, w_enc2, 256, enc_b2, ubf, 512, 256);
        // in_proj xm half -> slot3, K=512
        gemm_mfma<128,128,0,1><<<dim3(8, MR/128), blk, 0, stream>>>(
            ubf, 512, w_inpj, 512, nullptr, slot3, 1024, 512);
        // in_proj z half -> zbf, SILU fused (ACT=3)
        gemm_mfma<128,128,3,1><<<dim3(8, MR/128), blk, 0, stream>>>(
            ubf, 512, w_inpj + (size_t)1024 * 512, 512, nullptr, zbf, 1024, 512);
        // conv + silu: slot3 -> xms
        conv_silu_kernel<<<dim3(NB * (L/32), 4), blk, 0, stream>>>(
            slot3, conv_w, conv_b, xms, L);
        // x_proj: dbl = xms @ x_proj_w^T (MR x 64), K=1024
        gemm_mfma<64,64,0,1><<<dim3(1, MR/64), blk, 0, stream>>>(
            xms, 1024, w_xprj, 1024, nullptr, dblb, 64, 1024);
        // dt_proj + softplus: delta -> slot3, K=32
        gemm_mfma<128,128,2,1><<<dim3(8, MR/128), blk, 0, stream>>>(
            dblb, 64, w_dtpj, 32, dt_proj_b, slot3, 1024, 32);
        // scan: pass1 computes ylocal in place over xms + P,S
        scan_pass1<<<dim3(NB * NC, 4), blk, 0, stream>>>(
            slot3, xms, dblb, A_log, D_param, Pb, Sb, L);
        scan_pass2<<<dim3(NB * 64), blk, 0, stream>>>(Pb, Sb, Pb, NC);
        // pass3: correction-only; delta->y in place over slot3
        scan_pass3<<<dim3(NB * NC, 4), blk, 0, stream>>>(
            slot3, xms, dblb, A_log, Pb, zbf, L);
        // out_proj: o = y @ out_proj_w^T (MR x 512), K=1024
        gemm_mfma<128,128,0,1><<<dim3(4, MR/128), blk, 0, stream>>>(
            slot3, 1024, w_outp, 1024, nullptr, ubf, 512, 1024);
        // dec1: relu(o @ dec_w1^T + b1) (MR x 256), K=512
        gemm_mfma<64,128,1,1><<<dim3(2, MR/64), blk, 0, stream>>>(
            ubf, 512, w_dec1, 512, dec_b1, hbf, 256, 512);
        // dec2: out = h2 @ dec_w2^T + b2 (MR x 64 f32), K=256
        gemm_mfma<64,64,0,0><<<dim3(1, MR/64), blk, 0, stream>>>(
            hbf, 256, w_dec2, 256, dec_b2, outp, 64, 256);
    }
}

// Round 12
// 377.888 us; speedup vs baseline: 1.0427x; 1.0427x over previous
//
#include <hip/hip_runtime.h>
#include <hip/hip_bf16.h>

typedef __attribute__((ext_vector_type(8))) short bf16x8;
typedef __attribute__((ext_vector_type(4))) float f32x4;
typedef __attribute__((ext_vector_type(4))) unsigned short u16x4;
typedef __hip_bfloat16 bf16;

#define DEV __device__ __forceinline__
DEV float bf2f(bf16 v) { return __bfloat162float(v); }
DEV bf16  f2bf(float v) { return __float2bfloat16(v); }
DEV float sigmoidf_(float x) { return __builtin_amdgcn_rcpf(1.0f + __expf(-x)); }

// packed bf16x2 <-> two f32 (exact bit ops, no rounding change)
DEV void unpk(unsigned int v, float& lo, float& hi) {
    lo = __uint_as_float(v << 16);
    hi = __uint_as_float(v & 0xffff0000u);
}
DEV unsigned int pk(float lo, float hi) {
    bf16 a = f2bf(lo), b = f2bf(hi);
    return (unsigned int)*(unsigned short*)&a |
           ((unsigned int)*(unsigned short*)&b << 16);
}

typedef const __attribute__((address_space(1))) void* gptr_t;
typedef __attribute__((address_space(3))) void* lptr_t;

template<int N> DEV void waitcnt_vm() {
    if constexpr (N == 0) asm volatile("s_waitcnt vmcnt(0)" ::: "memory");
    else if constexpr (N == 2) asm volatile("s_waitcnt vmcnt(2)" ::: "memory");
    else if constexpr (N == 3) asm volatile("s_waitcnt vmcnt(3)" ::: "memory");
    else asm volatile("s_waitcnt vmcnt(4)" ::: "memory");
}

// ---------------------------------------------------------------------------
// bf16 MFMA GEMM (R8-verified): C = act(A @ W^T + bias)
// ACT: 0 none, 1 relu, 2 softplus, 3 silu. OUTBF: 1 bf16, 0 f32.
// ---------------------------------------------------------------------------
template<int BM, int BN, int ACT, int OUTBF>
__global__ __launch_bounds__(256)
void gemm_mfma(const bf16* __restrict__ A, int lda,
               const bf16* __restrict__ W, int ldw,
               const float* __restrict__ bias,
               void* __restrict__ Cp, int ldc, int K)
{
    constexpr int BK = 32;
    constexpr int WMS = BM / 2, WNS = BN / 2;
    constexpr int FM = WMS / 16, FN = WNS / 16;
    constexpr int AITER = (BM * BK) / (256 * 8);
    constexpr int BITER = (BN * BK) / (256 * 8);
    constexpr int NLD = AITER + BITER;
    constexpr int BUFB = (BM + BN) * BK * 2;

    __shared__ __align__(16) char smem[2 * BUFB];

    const int tid = threadIdx.x;
    const int lane = tid & 63;
    const int wid = tid >> 6;
    const int wm = wid >> 1, wn = wid & 1;
    const long m0 = (long)blockIdx.y * BM;
    const long n0 = (long)blockIdx.x * BN;

    f32x4 acc[FM][FN] = {};

    long aoff[AITER];
#pragma unroll
    for (int it = 0; it < AITER; ++it) {
        int q = it * 256 + tid;
        int r = q >> 2;
        aoff[it] = (long)(m0 + r) * lda * 2 + (((q & 3) * 16) ^ ((r & 3) << 4));
    }
    long boff[BITER];
#pragma unroll
    for (int it = 0; it < BITER; ++it) {
        int q = it * 256 + tid;
        int r = q >> 2;
        boff[it] = (long)(n0 + r) * ldw * 2 + (((q & 3) * 16) ^ ((r & 3) << 4));
    }

    const char* Ac = (const char*)A;
    const char* Wc = (const char*)W;

#pragma unroll
    for (int it = 0; it < AITER; ++it)
        __builtin_amdgcn_global_load_lds((gptr_t)(Ac + aoff[it]),
            (lptr_t)(smem + (it * 256 + wid * 64) * 16), 16, 0, 0);
#pragma unroll
    for (int it = 0; it < BITER; ++it)
        __builtin_amdgcn_global_load_lds((gptr_t)(Wc + boff[it]),
            (lptr_t)(smem + BM * BK * 2 + (it * 256 + wid * 64) * 16), 16, 0, 0);

    const int NK = K / BK;
    const int fr = lane & 15, fq = lane >> 4;
    const int swz = (fr & 3) << 4;
    int cur = 0;

    for (int ks = 0; ks < NK; ++ks) {
        if (ks + 1 < NK) {
            const long k2 = (long)(ks + 1) * BK * 2;
            char* dst = smem + (cur ^ 1) * BUFB;
#pragma unroll
            for (int it = 0; it < AITER; ++it)
                __builtin_amdgcn_global_load_lds((gptr_t)(Ac + aoff[it] + k2),
                    (lptr_t)(dst + (it * 256 + wid * 64) * 16), 16, 0, 0);
#pragma unroll
            for (int it = 0; it < BITER; ++it)
                __builtin_amdgcn_global_load_lds((gptr_t)(Wc + boff[it] + k2),
                    (lptr_t)(dst + BM * BK * 2 + (it * 256 + wid * 64) * 16), 16, 0, 0);
            waitcnt_vm<NLD>();
        } else {
            waitcnt_vm<0>();
        }
        __builtin_amdgcn_s_barrier();
        __builtin_amdgcn_sched_barrier(0);

        const char* base = smem + cur * BUFB;
        bf16x8 av[FM], bv[FN];
#pragma unroll
        for (int fm = 0; fm < FM; ++fm) {
            int ra = wm * WMS + fm * 16 + fr;
            av[fm] = *(const bf16x8*)(base + ra * 64 + ((fq * 16) ^ swz));
        }
#pragma unroll
        for (int fn = 0; fn < FN; ++fn) {
            int rb = wn * WNS + fn * 16 + fr;
            bv[fn] = *(const bf16x8*)(base + BM * BK * 2 + rb * 64 + ((fq * 16) ^ swz));
        }
#pragma unroll
        for (int fm = 0; fm < FM; ++fm)
#pragma unroll
            for (int fn = 0; fn < FN; ++fn)
                acc[fm][fn] = __builtin_amdgcn_mfma_f32_16x16x32_bf16(
                    av[fm], bv[fn], acc[fm][fn], 0, 0, 0);

        asm volatile("s_waitcnt lgkmcnt(0)" ::: "memory");
        __builtin_amdgcn_sched_barrier(0);
        __builtin_amdgcn_s_barrier();
        cur ^= 1;
    }

    float bcol[FN];
#pragma unroll
    for (int fn = 0; fn < FN; ++fn)
        bcol[fn] = bias ? bias[n0 + wn * WNS + fn * 16 + fr] : 0.0f;

    if constexpr (OUTBF) {
        constexpr int CST = BN + 8;
        bf16* ct = (bf16*)smem;
        for (int mh = 0; mh < BM / 64; ++mh) {
            __syncthreads();
            if (BM == 64 || wm == mh) {
#pragma unroll
                for (int fm = 0; fm < FM; ++fm) {
                    int lr0 = (BM == 64 ? wm * WMS : 0) + fm * 16 + fq * 4;
#pragma unroll
                    for (int fn = 0; fn < FN; ++fn) {
                        int lc = wn * WNS + fn * 16 + fr;
#pragma unroll
                        for (int r = 0; r < 4; ++r) {
                            float v = acc[fm][fn][r] + bcol[fn];
                            if (ACT == 1) v = fmaxf(v, 0.0f);
                            else if (ACT == 2)
                                v = fmaxf(v, 0.0f) + __logf(1.0f + __expf(-fabsf(v)));
                            else if (ACT == 3)
                                v = v * sigmoidf_(v);
                            ct[(lr0 + r) * CST + lc] = f2bf(v);
                        }
                    }
                }
            }
            __syncthreads();
            constexpr int GPR = BN / 8;
#pragma unroll
            for (int it = 0; it < (64 * GPR) / 256; ++it) {
                int idx = it * 256 + tid;
                int row = idx / GPR, cg = idx % GPR;
                bf16x8 v8 = *(const bf16x8*)&ct[row * CST + cg * 8];
                *(bf16x8*)((bf16*)Cp + (size_t)(m0 + mh * 64 + row) * ldc
                           + n0 + cg * 8) = v8;
            }
        }
    } else {
#pragma unroll
        for (int fn = 0; fn < FN; ++fn) {
            long col = n0 + wn * WNS + fn * 16 + fr;
#pragma unroll
            for (int fm = 0; fm < FM; ++fm) {
                long row0 = m0 + wm * WMS + fm * 16 + fq * 4;
#pragma unroll
                for (int r = 0; r < 4; ++r) {
                    float v = acc[fm][fn][r] + bcol[fn];
                    if (ACT == 1) v = fmaxf(v, 0.0f);
                    ((float*)Cp)[(size_t)(row0 + r) * ldc + col] = v;
                }
            }
        }
    }
}

// ---------------------------------------------------------------------------
struct CastJobs {
    const float* src[9];
    bf16* dst[9];
    int n[9];
};

__global__ __launch_bounds__(256)
void cast_bf16_kernel(CastJobs J)
{
    const int seg = blockIdx.y;
    const f32x4* s = (const f32x4*)J.src[seg];
    u16x4* d = (u16x4*)J.dst[seg];
    const int n4 = J.n[seg] >> 2;
    for (int i = blockIdx.x * 256 + threadIdx.x; i < n4; i += gridDim.x * 256) {
        f32x4 v = s[i];
        u16x4 o;
#pragma unroll
        for (int j = 0; j < 4; ++j) {
            bf16 b = f2bf(v[j]);
            o[j] = *(unsigned short*)&b;
        }
        d[i] = o;
    }
}

#define DSTATE 16
#define CHUNK 16      // scan chunk (NC = 128); V=2 channels/thread

// ---------------------------------------------------------------------------
// Depthwise causal conv (k=4) + bias + silu. bf16 in/out, f32 math.
// ---------------------------------------------------------------------------
__global__ __launch_bounds__(256)
void conv_silu_kernel(const bf16* __restrict__ xmr, const float* __restrict__ cw,
                      const float* __restrict__ cb, bf16* __restrict__ xms, int L)
{
    const int NCc = L / 32;
    const int c = blockIdx.x % NCc;
    const int b = blockIdx.x / NCc;
    const int d = blockIdx.y * 256 + threadIdx.x;

    const float w0 = cw[d * 4 + 0], w1 = cw[d * 4 + 1];
    const float w2 = cw[d * 4 + 2], w3 = cw[d * 4 + 3];
    const float bb = cb[d];

    const int t0 = c * 32;
    float x0 = 0.f, x1 = 0.f, x2 = 0.f;
    if (t0 >= 3) {
        x0 = bf2f(xmr[(size_t)(b * L + t0 - 3) * 1024 + d]);
        x1 = bf2f(xmr[(size_t)(b * L + t0 - 2) * 1024 + d]);
        x2 = bf2f(xmr[(size_t)(b * L + t0 - 1) * 1024 + d]);
    }
    for (int t = t0; t < t0 + 32; ++t) {
        float x3 = bf2f(xmr[(size_t)(b * L + t) * 1024 + d]);
        float v = fmaf(w0, x0, fmaf(w1, x1, fmaf(w2, x2, fmaf(w3, x3, bb))));
        xms[(size_t)(b * L + t) * 1024 + d] = f2bf(v * sigmoidf_(v));
        x0 = x1; x1 = x2; x2 = x3;
    }
}

// ---------------------------------------------------------------------------
// A helpers: fastA <=> A_s == -(s+1) (A_log = log(arange(1..16)) broadcast).
// chk_A returns the flag WITHOUT retaining the values (saves VGPRs).
// ---------------------------------------------------------------------------
DEV bool chk_A(const float* __restrict__ A_log, int d)
{
    bool f = true;
#pragma unroll
    for (int s = 0; s < DSTATE; ++s) {
        float v = -__expf(A_log[(size_t)d * DSTATE + s]);
        f = f && (fabsf(v + (float)(s + 1)) <= 1e-4f * (s + 1));
    }
    return f;
}

DEV void load_A(const float* __restrict__ A_log, int d, float* As_)
{
#pragma unroll
    for (int s = 0; s < DSTATE; ++s)
        As_[s] = -__expf(A_log[(size_t)d * DSTATE + s]);
}

// a[s] = r^(s+1), 15 muls, depth 5.
DEV void powa(float r, float* a)
{
    float r2 = r * r;
    float r3 = r2 * r;
    float r4 = r2 * r2;
    float r8 = r4 * r4;
    a[0] = r;       a[1] = r2;      a[2] = r3;      a[3] = r4;
    a[4] = r4 * r;  a[5] = r4 * r2; a[6] = r4 * r3; a[7] = r8;
    a[8] = r8 * r;  a[9] = r8 * r2; a[10] = r8 * r3; a[11] = r8 * r4;
    a[12] = a[11] * r; a[13] = a[11] * r2; a[14] = a[11] * r3; a[15] = r8 * r8;
}

// ---------------------------------------------------------------------------
// Scan pass 1 (V=2): thread owns channels (d0, d0+1); dword packed loads.
// Local scan; writes chunk-end S, P, and ylocal in place over xms.
// grid: (NB*NC, 2), block 256.
// ---------------------------------------------------------------------------
__global__ __launch_bounds__(256)
void scan_pass1(const bf16* __restrict__ delta, bf16* xms,
                const bf16* __restrict__ dblb, const float* __restrict__ A_log,
                const float* __restrict__ Dp,
                bf16* __restrict__ P, bf16* __restrict__ S, int L)
{
    const int NC = L / CHUNK;
    const int c = blockIdx.x % NC;
    const int b = blockIdx.x / NC;
    const int d0 = blockIdx.y * 512 + threadIdx.x * 2;

    __shared__ float Bsh[CHUNK][DSTATE];
    __shared__ float Csh[CHUNK][DSTATE];
    {
        int t = threadIdx.x >> 4, s = threadIdx.x & 15;
        size_t base = (size_t)(b * L + c * CHUNK + t) * 64;
        Bsh[t][s] = bf2f(dblb[base + 32 + s]);
        Csh[t][s] = bf2f(dblb[base + 48 + s]);
    }
    __syncthreads();

    const bool fastA = chk_A(A_log, d0) && chk_A(A_log, d0 + 1);
    const float Dd0 = Dp[d0], Dd1 = Dp[d0 + 1];

    float h0[DSTATE], h1[DSTATE];
#pragma unroll
    for (int s = 0; s < DSTATE; ++s) { h0[s] = 0.f; h1[s] = 0.f; }

    const size_t rb = (size_t)(b * L + c * CHUNK);

    if (fastA) {
        float sum0 = 0.f, sum1 = 0.f;
        for (int t = 0; t < CHUNK; ++t) {
            size_t g = (rb + t) * 1024 + d0;
            float de0, de1, x0, x1;
            unpk(*(const unsigned int*)&delta[g], de0, de1);
            unpk(*(const unsigned int*)&xms[g], x0, x1);
            float dx0 = de0 * x0, dx1 = de1 * x1;
            float a0[DSTATE], a1[DSTATE];
            powa(__expf(-de0), a0);
            powa(__expf(-de1), a1);
            sum0 += de0; sum1 += de1;
            float y0 = x0 * Dd0, y1 = x1 * Dd1;
#pragma unroll
            for (int s = 0; s < DSTATE; ++s) {
                h0[s] = fmaf(a0[s], h0[s], dx0 * Bsh[t][s]);
                y0 = fmaf(h0[s], Csh[t][s], y0);
                h1[s] = fmaf(a1[s], h1[s], dx1 * Bsh[t][s]);
                y1 = fmaf(h1[s], Csh[t][s], y1);
            }
            *(unsigned int*)&xms[g] = pk(y0, y1);
        }
        float pa0[DSTATE], pa1[DSTATE];
        powa(__expf(-sum0), pa0);
        powa(__expf(-sum1), pa1);
#pragma unroll
        for (int s = 0; s < DSTATE; ++s) {
            size_t o = ((size_t)(b * NC + c) * DSTATE + s) * 1024 + d0;
            *(unsigned int*)&P[o] = pk(pa0[s], pa1[s]);
            *(unsigned int*)&S[o] = pk(h0[s], h1[s]);
        }
    } else {
        float As0[DSTATE], As1[DSTATE];
        load_A(A_log, d0, As0);
        load_A(A_log, d0 + 1, As1);
        float p0[DSTATE], p1[DSTATE];
#pragma unroll
        for (int s = 0; s < DSTATE; ++s) { p0[s] = 1.f; p1[s] = 1.f; }
        for (int t = 0; t < CHUNK; ++t) {
            size_t g = (rb + t) * 1024 + d0;
            float de0, de1, x0, x1;
            unpk(*(const unsigned int*)&delta[g], de0, de1);
            unpk(*(const unsigned int*)&xms[g], x0, x1);
            float dx0 = de0 * x0, dx1 = de1 * x1;
            float y0 = x0 * Dd0, y1 = x1 * Dd1;
#pragma unroll
            for (int s = 0; s < DSTATE; ++s) {
                float dA0 = __expf(de0 * As0[s]);
                float dA1 = __expf(de1 * As1[s]);
                h0[s] = fmaf(dA0, h0[s], dx0 * Bsh[t][s]);
                p0[s] *= dA0;
                y0 = fmaf(h0[s], Csh[t][s], y0);
                h1[s] = fmaf(dA1, h1[s], dx1 * Bsh[t][s]);
                p1[s] *= dA1;
                y1 = fmaf(h1[s], Csh[t][s], y1);
            }
            *(unsigned int*)&xms[g] = pk(y0, y1);
        }
#pragma unroll
        for (int s = 0; s < DSTATE; ++s) {
            size_t o = ((size_t)(b * NC + c) * DSTATE + s) * 1024 + d0;
            *(unsigned int*)&P[o] = pk(p0[s], p1[s]);
            *(unsigned int*)&S[o] = pk(h0[s], h1[s]);
        }
    }
}

// ---------------------------------------------------------------------------
// Pass 2 (V=2): serial combine over NC chunks, 8-deep batched dword loads.
// Hinit in place of P. grid: NB*32 blocks of 256.
// ---------------------------------------------------------------------------
__global__ __launch_bounds__(256)
void scan_pass2(const bf16* P, const bf16* __restrict__ S, bf16* Hinit, int NC)
{
    int g = blockIdx.x * 256 + threadIdx.x;
    int dp = (g & 511) * 2;
    int s = (g >> 9) & 15;
    int b = g >> 13;
    const size_t cs = (size_t)DSTATE * 1024;
    size_t o = ((size_t)(b * NC) * DSTATE + s) * 1024 + dp;
    float h0 = 0.f, h1 = 0.f;
    for (int c0 = 0; c0 < NC; c0 += 8) {
        float pv0[8], pv1[8], sv0[8], sv1[8];
#pragma unroll
        for (int j = 0; j < 8; ++j) {
            unpk(*(const unsigned int*)&P[o + j * cs], pv0[j], pv1[j]);
            unpk(*(const unsigned int*)&S[o + j * cs], sv0[j], sv1[j]);
        }
#pragma unroll
        for (int j = 0; j < 8; ++j) {
            *(unsigned int*)&Hinit[o + j * cs] = pk(h0, h1);
            h0 = fmaf(pv0[j], h0, sv0[j]);
            h1 = fmaf(pv1[j], h1, sv1[j]);
        }
        o += 8 * cs;
    }
}

// ---------------------------------------------------------------------------
// Pass 3 (V=2, correction-only): dY holds delta in, y*z out (same buffer).
// y_t = ylocal_t + sum_s C_t[s]*w_t[s]; w updated multiplicatively.
// grid: (NB*NC, 2), block 256.
// ---------------------------------------------------------------------------
__global__ __launch_bounds__(256)
void scan_pass3(bf16* dY, const bf16* __restrict__ ylocal,
                const bf16* __restrict__ dblb, const float* __restrict__ A_log,
                const bf16* __restrict__ Hinit,
                const bf16* __restrict__ zs, int L)
{
    const int NC = L / CHUNK;
    const int c = blockIdx.x % NC;
    const int b = blockIdx.x / NC;
    const int d0 = blockIdx.y * 512 + threadIdx.x * 2;

    __shared__ float Csh[CHUNK][DSTATE];
    {
        int t = threadIdx.x >> 4, s = threadIdx.x & 15;
        Csh[t][s] = bf2f(dblb[(size_t)(b * L + c * CHUNK + t) * 64 + 48 + s]);
    }
    __syncthreads();

    const bool fastA = chk_A(A_log, d0) && chk_A(A_log, d0 + 1);

    float w0[DSTATE], w1[DSTATE];
#pragma unroll
    for (int s = 0; s < DSTATE; ++s) {
        size_t o = ((size_t)(b * NC + c) * DSTATE + s) * 1024 + d0;
        unpk(*(const unsigned int*)&Hinit[o], w0[s], w1[s]);
    }

    const size_t rb = (size_t)(b * L + c * CHUNK);

    if (fastA) {
        for (int t = 0; t < CHUNK; ++t) {
            size_t g = (rb + t) * 1024 + d0;
            float de0, de1, yl0, yl1, z0, z1;
            unpk(*(const unsigned int*)&dY[g], de0, de1);
            unpk(*(const unsigned int*)&ylocal[g], yl0, yl1);
            unpk(*(const unsigned int*)&zs[g], z0, z1);
            float a0[DSTATE], a1[DSTATE];
            powa(__expf(-de0), a0);
            powa(__expf(-de1), a1);
            float c00 = 0.f, c01 = 0.f, c10 = 0.f, c11 = 0.f;
#pragma unroll
            for (int s = 0; s < DSTATE; s += 2) {
                w0[s] *= a0[s];
                c00 = fmaf(w0[s], Csh[t][s], c00);
                w0[s+1] *= a0[s+1];
                c01 = fmaf(w0[s+1], Csh[t][s+1], c01);
                w1[s] *= a1[s];
                c10 = fmaf(w1[s], Csh[t][s], c10);
                w1[s+1] *= a1[s+1];
                c11 = fmaf(w1[s+1], Csh[t][s+1], c11);
            }
            *(unsigned int*)&dY[g] =
                pk((yl0 + c00 + c01) * z0, (yl1 + c10 + c11) * z1);
        }
    } else {
        float As0[DSTATE], As1[DSTATE];
        load_A(A_log, d0, As0);
        load_A(A_log, d0 + 1, As1);
        for (int t = 0; t < CHUNK; ++t) {
            size_t g = (rb + t) * 1024 + d0;
            float de0, de1, yl0, yl1, z0, z1;
            unpk(*(const unsigned int*)&dY[g], de0, de1);
            unpk(*(const unsigned int*)&ylocal[g], yl0, yl1);
            unpk(*(const unsigned int*)&zs[g], z0, z1);
            float c00 = 0.f, c10 = 0.f;
#pragma unroll
            for (int s = 0; s < DSTATE; ++s) {
                w0[s] *= __expf(de0 * As0[s]);
                c00 = fmaf(w0[s], Csh[t][s], c00);
                w1[s] *= __expf(de1 * As1[s]);
                c10 = fmaf(w1[s], Csh[t][s], c10);
            }
            *(unsigned int*)&dY[g] = pk((yl0 + c00) * z0, (yl1 + c10) * z1);
        }
    }
}

// ---------------------------------------------------------------------------

extern "C" void kernel_launch(void* const* d_in, const int* in_sizes, int n_in,
                              void* d_out, int out_size, void* d_ws, size_t ws_size,
                              hipStream_t stream)
{
    (void)in_sizes; (void)n_in; (void)out_size;

    const float* x         = (const float*)d_in[0];
    const float* enc_w1    = (const float*)d_in[1];
    const float* enc_b1    = (const float*)d_in[2];
    const float* enc_w2    = (const float*)d_in[3];
    const float* enc_b2    = (const float*)d_in[4];
    const float* in_proj_w = (const float*)d_in[5];
    const float* conv_w    = (const float*)d_in[6];
    const float* conv_b    = (const float*)d_in[7];
    const float* x_proj_w  = (const float*)d_in[8];
    const float* dt_proj_w = (const float*)d_in[9];
    const float* dt_proj_b = (const float*)d_in[10];
    const float* A_log     = (const float*)d_in[11];
    const float* D_param   = (const float*)d_in[12];
    const float* out_proj_w= (const float*)d_in[13];
    const float* dec_w1    = (const float*)d_in[14];
    const float* dec_b1    = (const float*)d_in[15];
    const float* dec_w2    = (const float*)d_in[16];
    const float* dec_b2    = (const float*)d_in[17];
    float* out = (float*)d_out;

    const int L = 2048, NC = L / CHUNK;   // NC = 128

    // ---- bf16 fixed region (weights + x) ----
    bf16* wb = (bf16*)d_ws;
    size_t off = 0;
    bf16* w_enc1 = wb + off; off += 16384;
    bf16* w_enc2 = wb + off; off += 131072;
    bf16* w_inpj = wb + off; off += 1048576;
    bf16* w_xprj = wb + off; off += 65536;
    bf16* w_dtpj = wb + off; off += 32768;
    bf16* w_outp = wb + off; off += 524288;
    bf16* w_dec1 = wb + off; off += 131072;
    bf16* w_dec2 = wb + off; off += 16384;
    bf16* xbf    = wb + off; off += 1048576;
    const size_t fixedB = off * 2;         // 6,029,312 B

    // per-row bytes: hbf(512)+ubf(1024)+slot3(2048)+zbf(2048)+xms(2048)
    //               +dblb(128)+Pb(2048)+Sb(2048) = 11904
    const size_t PER_ROW = 11904;
    int SPLIT = 8;
    if      (fixedB + (size_t)16384 * PER_ROW <= ws_size) SPLIT = 1;
    else if (fixedB + (size_t) 8192 * PER_ROW <= ws_size) SPLIT = 2;  // 103.5 MB (proven fit)
    else if (fixedB + (size_t) 4096 * PER_ROW <= ws_size) SPLIT = 4;

    const int NB = 8 / SPLIT;
    const int MR = NB * L;

    char* pb = (char*)d_ws + fixedB;
    bf16* hbf   = (bf16*)pb;                     // MR x 256
    bf16* ubf   = hbf   + (size_t)MR * 256;      // MR x 512 (u, o)
    bf16* slot3 = ubf   + (size_t)MR * 512;      // MR x 1024 (xm_raw -> delta -> y)
    bf16* zbf   = slot3 + (size_t)MR * 1024;     // MR x 1024 (silu'd z)
    bf16* xms   = zbf   + (size_t)MR * 1024;     // MR x 1024 (xm_silu -> ylocal)
    bf16* dblb  = xms   + (size_t)MR * 1024;     // MR x 64
    bf16* Pb    = dblb  + (size_t)MR * 64;       // MR x 1024 bf16 (-> Hinit)
    bf16* Sb    = Pb    + (size_t)MR * 1024;     // MR x 1024 bf16

    CastJobs J;
    J.src[0] = enc_w1;     J.dst[0] = w_enc1; J.n[0] = 16384;
    J.src[1] = enc_w2;     J.dst[1] = w_enc2; J.n[1] = 131072;
    J.src[2] = in_proj_w;  J.dst[2] = w_inpj; J.n[2] = 1048576;
    J.src[3] = x_proj_w;   J.dst[3] = w_xprj; J.n[3] = 65536;
    J.src[4] = dt_proj_w;  J.dst[4] = w_dtpj; J.n[4] = 32768;
    J.src[5] = out_proj_w; J.dst[5] = w_outp; J.n[5] = 524288;
    J.src[6] = dec_w1;     J.dst[6] = w_dec1; J.n[6] = 131072;
    J.src[7] = dec_w2;     J.dst[7] = w_dec2; J.n[7] = 16384;
    J.src[8] = x;          J.dst[8] = xbf;    J.n[8] = 1048576;
    cast_bf16_kernel<<<dim3(128, 9), 256, 0, stream>>>(J);

    dim3 blk(256);
    for (int p = 0; p < SPLIT; ++p) {
        const bf16* xp  = xbf + (size_t)p * MR * 64;
        float*     outp = out + (size_t)p * MR * 64;

        // enc1: relu(x @ enc_w1^T + b1) -> h (MR x 256), K=64
        gemm_mfma<64,128,1,1><<<dim3(2, MR/64), blk, 0, stream>>>(
            xp, 64, w_enc1, 64, enc_b1, hbf, 256, 64);
        // enc2: u = h @ enc_w2^T + b2 (MR x 512), K=256
        gemm_mfma<128,128,0,1><<<dim3(4, MR/128), blk, 0, stream>>>(
            hbf, 256, w_enc2, 256, enc_b2, ubf, 512, 256);
        // in_proj xm half -> slot3, K=512
        gemm_mfma<128,128,0,1><<<dim3(8, MR/128), blk, 0, stream>>>(
            ubf, 512, w_inpj, 512, nullptr, slot3, 1024, 512);
        // in_proj z half -> zbf, SILU fused (ACT=3)
        gemm_mfma<128,128,3,1><<<dim3(8, MR/128), blk, 0, stream>>>(
            ubf, 512, w_inpj + (size_t)1024 * 512, 512, nullptr, zbf, 1024, 512);
        // conv + silu: slot3 -> xms
        conv_silu_kernel<<<dim3(NB * (L/32), 4), blk, 0, stream>>>(
            slot3, conv_w, conv_b, xms, L);
        // x_proj: dbl = xms @ x_proj_w^T (MR x 64), K=1024
        gemm_mfma<64,64,0,1><<<dim3(1, MR/64), blk, 0, stream>>>(
            xms, 1024, w_xprj, 1024, nullptr, dblb, 64, 1024);
        // dt_proj + softplus: delta -> slot3, K=32
        gemm_mfma<128,128,2,1><<<dim3(8, MR/128), blk, 0, stream>>>(
            dblb, 64, w_dtpj, 32, dt_proj_b, slot3, 1024, 32);
        // scan: pass1 computes ylocal in place over xms + P,S
        scan_pass1<<<dim3(NB * NC, 2), blk, 0, stream>>>(
            slot3, xms, dblb, A_log, D_param, Pb, Sb, L);
        scan_pass2<<<dim3(NB * 32), blk, 0, stream>>>(Pb, Sb, Pb, NC);
        // pass3: correction-only; delta->y in place over slot3
        scan_pass3<<<dim3(NB * NC, 2), blk, 0, stream>>>(
            slot3, xms, dblb, A_log, Pb, zbf, L);
        // out_proj: o = y @ out_proj_w^T (MR x 512), K=1024
        gemm_mfma<128,128,0,1><<<dim3(4, MR/128), blk, 0, stream>>>(
            slot3, 1024, w_outp, 1024, nullptr, ubf, 512, 1024);
        // dec1: relu(o @ dec_w1^T + b1) (MR x 256), K=512
        gemm_mfma<64,128,1,1><<<dim3(2, MR/64), blk, 0, stream>>>(
            ubf, 512, w_dec1, 512, dec_b1, hbf, 256, 512);
        // dec2: out = h2 @ dec_w2^T + b2 (MR x 64 f32), K=256
        gemm_mfma<64,64,0,0><<<dim3(1, MR/64), blk, 0, stream>>>(
            hbf, 256, w_dec2, 256, dec_b2, outp, 64, 256);
    }
}

// Round 13
// 371.488 us; speedup vs baseline: 1.0606x; 1.0172x over previous
//
#include <hip/hip_runtime.h>
#include <hip/hip_bf16.h>

typedef __attribute__((ext_vector_type(8))) short bf16x8;
typedef __attribute__((ext_vector_type(4))) float f32x4;
typedef __attribute__((ext_vector_type(4))) unsigned short u16x4;
typedef __hip_bfloat16 bf16;

#define DEV __device__ __forceinline__
DEV float bf2f(bf16 v) { return __bfloat162float(v); }
DEV bf16  f2bf(float v) { return __float2bfloat16(v); }
DEV float sigmoidf_(float x) { return __builtin_amdgcn_rcpf(1.0f + __expf(-x)); }

typedef const __attribute__((address_space(1))) void* gptr_t;
typedef __attribute__((address_space(3))) void* lptr_t;

template<int N> DEV void waitcnt_vm() {
    if constexpr (N == 0) asm volatile("s_waitcnt vmcnt(0)" ::: "memory");
    else if constexpr (N == 2) asm volatile("s_waitcnt vmcnt(2)" ::: "memory");
    else if constexpr (N == 3) asm volatile("s_waitcnt vmcnt(3)" ::: "memory");
    else asm volatile("s_waitcnt vmcnt(4)" ::: "memory");
}

template<int A> DEV float actf(float v) {
    if constexpr (A == 1) return fmaxf(v, 0.0f);
    else if constexpr (A == 2) return fmaxf(v, 0.0f) + __logf(1.0f + __expf(-fabsf(v)));
    else if constexpr (A == 3) return v * sigmoidf_(v);
    else return v;
}

// ---------------------------------------------------------------------------
// bf16 MFMA GEMM (R8-verified core): C = act(A @ W^T + bias)
// DUAL=1: blocks with n0>=NH write act2(...) to Cp2 at column n0-NH
// (used to fuse in_proj's xm and z halves into one launch).
// ---------------------------------------------------------------------------
template<int BM, int BN, int ACT, int OUTBF, int DUAL, int ACT2>
__global__ __launch_bounds__(256)
void gemm_mfma(const bf16* __restrict__ A, int lda,
               const bf16* __restrict__ W, int ldw,
               const float* __restrict__ bias,
               void* __restrict__ Cp, void* __restrict__ Cp2, int NH,
               int ldc, int K)
{
    constexpr int BK = 32;
    constexpr int WMS = BM / 2, WNS = BN / 2;
    constexpr int FM = WMS / 16, FN = WNS / 16;
    constexpr int AITER = (BM * BK) / (256 * 8);
    constexpr int BITER = (BN * BK) / (256 * 8);
    constexpr int NLD = AITER + BITER;
    constexpr int BUFB = (BM + BN) * BK * 2;

    __shared__ __align__(16) char smem[2 * BUFB];

    const int tid = threadIdx.x;
    const int lane = tid & 63;
    const int wid = tid >> 6;
    const int wm = wid >> 1, wn = wid & 1;
    const long m0 = (long)blockIdx.y * BM;
    const long n0 = (long)blockIdx.x * BN;

    f32x4 acc[FM][FN] = {};

    long aoff[AITER];
#pragma unroll
    for (int it = 0; it < AITER; ++it) {
        int q = it * 256 + tid;
        int r = q >> 2;
        aoff[it] = (long)(m0 + r) * lda * 2 + (((q & 3) * 16) ^ ((r & 3) << 4));
    }
    long boff[BITER];
#pragma unroll
    for (int it = 0; it < BITER; ++it) {
        int q = it * 256 + tid;
        int r = q >> 2;
        boff[it] = (long)(n0 + r) * ldw * 2 + (((q & 3) * 16) ^ ((r & 3) << 4));
    }

    const char* Ac = (const char*)A;
    const char* Wc = (const char*)W;

#pragma unroll
    for (int it = 0; it < AITER; ++it)
        __builtin_amdgcn_global_load_lds((gptr_t)(Ac + aoff[it]),
            (lptr_t)(smem + (it * 256 + wid * 64) * 16), 16, 0, 0);
#pragma unroll
    for (int it = 0; it < BITER; ++it)
        __builtin_amdgcn_global_load_lds((gptr_t)(Wc + boff[it]),
            (lptr_t)(smem + BM * BK * 2 + (it * 256 + wid * 64) * 16), 16, 0, 0);

    const int NK = K / BK;
    const int fr = lane & 15, fq = lane >> 4;
    const int swz = (fr & 3) << 4;
    int cur = 0;

    for (int ks = 0; ks < NK; ++ks) {
        if (ks + 1 < NK) {
            const long k2 = (long)(ks + 1) * BK * 2;
            char* dst = smem + (cur ^ 1) * BUFB;
#pragma unroll
            for (int it = 0; it < AITER; ++it)
                __builtin_amdgcn_global_load_lds((gptr_t)(Ac + aoff[it] + k2),
                    (lptr_t)(dst + (it * 256 + wid * 64) * 16), 16, 0, 0);
#pragma unroll
            for (int it = 0; it < BITER; ++it)
                __builtin_amdgcn_global_load_lds((gptr_t)(Wc + boff[it] + k2),
                    (lptr_t)(dst + BM * BK * 2 + (it * 256 + wid * 64) * 16), 16, 0, 0);
            waitcnt_vm<NLD>();
        } else {
            waitcnt_vm<0>();
        }
        __builtin_amdgcn_s_barrier();
        __builtin_amdgcn_sched_barrier(0);

        const char* base = smem + cur * BUFB;
        bf16x8 av[FM], bv[FN];
#pragma unroll
        for (int fm = 0; fm < FM; ++fm) {
            int ra = wm * WMS + fm * 16 + fr;
            av[fm] = *(const bf16x8*)(base + ra * 64 + ((fq * 16) ^ swz));
        }
#pragma unroll
        for (int fn = 0; fn < FN; ++fn) {
            int rb = wn * WNS + fn * 16 + fr;
            bv[fn] = *(const bf16x8*)(base + BM * BK * 2 + rb * 64 + ((fq * 16) ^ swz));
        }
#pragma unroll
        for (int fm = 0; fm < FM; ++fm)
#pragma unroll
            for (int fn = 0; fn < FN; ++fn)
                acc[fm][fn] = __builtin_amdgcn_mfma_f32_16x16x32_bf16(
                    av[fm], bv[fn], acc[fm][fn], 0, 0, 0);

        asm volatile("s_waitcnt lgkmcnt(0)" ::: "memory");
        __builtin_amdgcn_sched_barrier(0);
        __builtin_amdgcn_s_barrier();
        cur ^= 1;
    }

    float bcol[FN];
#pragma unroll
    for (int fn = 0; fn < FN; ++fn)
        bcol[fn] = bias ? bias[n0 + wn * WNS + fn * 16 + fr] : 0.0f;

    // dual-destination resolution (wave-uniform)
    void* dstP = Cp;
    long nb0 = n0;
    bool use2 = false;
    if (DUAL && n0 >= NH) { dstP = Cp2; nb0 = n0 - NH; use2 = true; }

    if constexpr (OUTBF) {
        constexpr int CST = BN + 8;
        bf16* ct = (bf16*)smem;
        for (int mh = 0; mh < BM / 64; ++mh) {
            __syncthreads();
            if (BM == 64 || wm == mh) {
#pragma unroll
                for (int fm = 0; fm < FM; ++fm) {
                    int lr0 = (BM == 64 ? wm * WMS : 0) + fm * 16 + fq * 4;
#pragma unroll
                    for (int fn = 0; fn < FN; ++fn) {
                        int lc = wn * WNS + fn * 16 + fr;
#pragma unroll
                        for (int r = 0; r < 4; ++r) {
                            float v = acc[fm][fn][r] + bcol[fn];
                            v = (DUAL && use2) ? actf<ACT2>(v) : actf<ACT>(v);
                            ct[(lr0 + r) * CST + lc] = f2bf(v);
                        }
                    }
                }
            }
            __syncthreads();
            constexpr int GPR = BN / 8;
#pragma unroll
            for (int it = 0; it < (64 * GPR) / 256; ++it) {
                int idx = it * 256 + tid;
                int row = idx / GPR, cg = idx % GPR;
                bf16x8 v8 = *(const bf16x8*)&ct[row * CST + cg * 8];
                *(bf16x8*)((bf16*)dstP + (size_t)(m0 + mh * 64 + row) * ldc
                           + nb0 + cg * 8) = v8;
            }
        }
    } else {
#pragma unroll
        for (int fn = 0; fn < FN; ++fn) {
            long col = n0 + wn * WNS + fn * 16 + fr;
#pragma unroll
            for (int fm = 0; fm < FM; ++fm) {
                long row0 = m0 + wm * WMS + fm * 16 + fq * 4;
#pragma unroll
                for (int r = 0; r < 4; ++r) {
                    float v = acc[fm][fn][r] + bcol[fn];
                    v = actf<ACT>(v);
                    ((float*)Cp)[(size_t)(row0 + r) * ldc + col] = v;
                }
            }
        }
    }
}

// ---------------------------------------------------------------------------
struct CastJobs {
    const float* src[9];
    bf16* dst[9];
    int n[9];
};

__global__ __launch_bounds__(256)
void cast_bf16_kernel(CastJobs J)
{
    const int seg = blockIdx.y;
    const f32x4* s = (const f32x4*)J.src[seg];
    u16x4* d = (u16x4*)J.dst[seg];
    const int n4 = J.n[seg] >> 2;
    for (int i = blockIdx.x * 256 + threadIdx.x; i < n4; i += gridDim.x * 256) {
        f32x4 v = s[i];
        u16x4 o;
#pragma unroll
        for (int j = 0; j < 4; ++j) {
            bf16 b = f2bf(v[j]);
            o[j] = *(unsigned short*)&b;
        }
        d[i] = o;
    }
}

#define DSTATE 16
#define CHUNK 32      // scan chunk (NC = 64) — R10-verified config

// ---------------------------------------------------------------------------
// Depthwise causal conv (k=4) + bias + silu. bf16 in/out, f32 math.
// ---------------------------------------------------------------------------
__global__ __launch_bounds__(256)
void conv_silu_kernel(const bf16* __restrict__ xmr, const float* __restrict__ cw,
                      const float* __restrict__ cb, bf16* __restrict__ xms, int L)
{
    const int NCc = L / 32;
    const int c = blockIdx.x % NCc;
    const int b = blockIdx.x / NCc;
    const int d = blockIdx.y * 256 + threadIdx.x;

    const float w0 = cw[d * 4 + 0], w1 = cw[d * 4 + 1];
    const float w2 = cw[d * 4 + 2], w3 = cw[d * 4 + 3];
    const float bb = cb[d];

    const int t0 = c * 32;
    float x0 = 0.f, x1 = 0.f, x2 = 0.f;
    if (t0 >= 3) {
        x0 = bf2f(xmr[(size_t)(b * L + t0 - 3) * 1024 + d]);
        x1 = bf2f(xmr[(size_t)(b * L + t0 - 2) * 1024 + d]);
        x2 = bf2f(xmr[(size_t)(b * L + t0 - 1) * 1024 + d]);
    }
    for (int t = t0; t < t0 + 32; ++t) {
        float x3 = bf2f(xmr[(size_t)(b * L + t) * 1024 + d]);
        float v = fmaf(w0, x0, fmaf(w1, x1, fmaf(w2, x2, fmaf(w3, x3, bb))));
        xms[(size_t)(b * L + t) * 1024 + d] = f2bf(v * sigmoidf_(v));
        x0 = x1; x1 = x2; x2 = x3;
    }
}

// ---------------------------------------------------------------------------
// A helper: detect A_s == -(s+1) (A_log = log(arange(1..16)) broadcast).
// ---------------------------------------------------------------------------
DEV bool load_A(const float* __restrict__ A_log, int d, float* As_)
{
    bool fastA = true;
#pragma unroll
    for (int s = 0; s < DSTATE; ++s) {
        As_[s] = -__expf(A_log[(size_t)d * DSTATE + s]);
        fastA = fastA && (fabsf(As_[s] + (float)(s + 1)) <= 1e-4f * (s + 1));
    }
    return fastA;
}

// a[s] = r^(s+1), 15 muls, depth 5.
DEV void powa(float r, float* a)
{
    float r2 = r * r;
    float r3 = r2 * r;
    float r4 = r2 * r2;
    float r8 = r4 * r4;
    a[0] = r;       a[1] = r2;      a[2] = r3;      a[3] = r4;
    a[4] = r4 * r;  a[5] = r4 * r2; a[6] = r4 * r3; a[7] = r8;
    a[8] = r8 * r;  a[9] = r8 * r2; a[10] = r8 * r3; a[11] = r8 * r4;
    a[12] = a[11] * r; a[13] = a[11] * r2; a[14] = a[11] * r3; a[15] = r8 * r8;
}

// ---------------------------------------------------------------------------
// Scan pass 1 (R10 structure + FUSED dt_proj/softplus):
//  delta_d,t = softplus(dot(dbl[t][0:32], Wdt[d]) + dtb[d]) — computed here,
//  rounded to bf16 BEFORE use (numerics identical to the GEMM path), written
//  to delta_out (slot3) for pass3. Then local scan: ylocal in place over xms,
//  chunk-end P,S.
// ---------------------------------------------------------------------------
__global__ __launch_bounds__(256)
void scan_pass1(bf16* __restrict__ delta_out, bf16* xms,
                const bf16* __restrict__ dblb,
                const bf16* __restrict__ wdt, const float* __restrict__ dtb,
                const float* __restrict__ A_log, const float* __restrict__ Dp,
                bf16* __restrict__ P, bf16* __restrict__ S, int L)
{
    const int NC = L / CHUNK;
    const int c = blockIdx.x % NC;
    const int b = blockIdx.x / NC;
    const int d = blockIdx.y * 256 + threadIdx.x;

    __shared__ float Bsh[CHUNK][DSTATE];
    __shared__ float Csh[CHUNK][DSTATE];
    __shared__ float Tsh[CHUNK][33];       // dt-row (32 cols, +1 pad)
#pragma unroll
    for (int it = 0; it < CHUNK * DSTATE / 256; ++it) {
        int idx = threadIdx.x + it * 256;
        int t = idx >> 4, s = idx & 15;
        size_t base = (size_t)(b * L + c * CHUNK + t) * 64;
        Bsh[t][s] = bf2f(dblb[base + 32 + s]);
        Csh[t][s] = bf2f(dblb[base + 48 + s]);
    }
#pragma unroll
    for (int it = 0; it < CHUNK * 32 / 256; ++it) {
        int idx = threadIdx.x + it * 256;
        int t = idx >> 5, k = idx & 31;
        Tsh[t][k] = bf2f(dblb[(size_t)(b * L + c * CHUNK + t) * 64 + k]);
    }
    __syncthreads();

    // per-thread dt weight row (32 bf16, vector-loaded)
    float wd[32];
    {
        bf16x8 wv[4];
#pragma unroll
        for (int j = 0; j < 4; ++j)
            wv[j] = *(const bf16x8*)&wdt[(size_t)d * 32 + j * 8];
#pragma unroll
        for (int j = 0; j < 4; ++j)
#pragma unroll
            for (int e = 0; e < 8; ++e) {
                short sv = wv[j][e];
                wd[j * 8 + e] = bf2f(*(bf16*)&sv);
            }
    }
    const float bias_d = dtb[d];

    float As_[DSTATE];
    const bool fastA = load_A(A_log, d, As_);
    const float Dd = Dp[d];

    float h[DSTATE];
#pragma unroll
    for (int s = 0; s < DSTATE; ++s) h[s] = 0.f;

    const size_t rb = (size_t)(b * L + c * CHUNK);

    if (fastA) {
        float sumd = 0.f;
        for (int t = 0; t < CHUNK; ++t) {
            size_t g = (rb + t) * 1024 + d;
            // fused dt_proj + softplus
            float v0 = 0.f, v1 = 0.f, v2 = 0.f, v3 = 0.f;
#pragma unroll
            for (int k = 0; k < 32; k += 4) {
                v0 = fmaf(Tsh[t][k],     wd[k],     v0);
                v1 = fmaf(Tsh[t][k + 1], wd[k + 1], v1);
                v2 = fmaf(Tsh[t][k + 2], wd[k + 2], v2);
                v3 = fmaf(Tsh[t][k + 3], wd[k + 3], v3);
            }
            float v = (v0 + v1) + (v2 + v3) + bias_d;
            float sp = fmaxf(v, 0.0f) + __logf(1.0f + __expf(-fabsf(v)));
            bf16 dbf = f2bf(sp);
            delta_out[g] = dbf;
            float de = bf2f(dbf);          // use rounded value (== GEMM path)

            float x  = bf2f(xms[g]);
            float dx = de * x;
            float r = __expf(-de);
            float a[DSTATE];
            powa(r, a);
            sumd += de;
            float yl = x * Dd;
#pragma unroll
            for (int s = 0; s < DSTATE; ++s) {
                h[s] = fmaf(a[s], h[s], dx * Bsh[t][s]);
                yl = fmaf(h[s], Csh[t][s], yl);
            }
            xms[g] = f2bf(yl);
        }
        float Rc = __expf(-sumd);
        float pa[DSTATE];
        powa(Rc, pa);
#pragma unroll
        for (int s = 0; s < DSTATE; ++s) {
            size_t o = ((size_t)(b * NC + c) * DSTATE + s) * 1024 + d;
            P[o] = f2bf(pa[s]);
            S[o] = f2bf(h[s]);
        }
    } else {
        float p[DSTATE];
#pragma unroll
        for (int s = 0; s < DSTATE; ++s) p[s] = 1.f;
        for (int t = 0; t < CHUNK; ++t) {
            size_t g = (rb + t) * 1024 + d;
            float v0 = 0.f, v1 = 0.f;
#pragma unroll
            for (int k = 0; k < 32; k += 2) {
                v0 = fmaf(Tsh[t][k],     wd[k],     v0);
                v1 = fmaf(Tsh[t][k + 1], wd[k + 1], v1);
            }
            float v = v0 + v1 + bias_d;
            float sp = fmaxf(v, 0.0f) + __logf(1.0f + __expf(-fabsf(v)));
            bf16 dbf = f2bf(sp);
            delta_out[g] = dbf;
            float de = bf2f(dbf);

            float x  = bf2f(xms[g]);
            float dx = de * x;
            float yl = x * Dd;
#pragma unroll
            for (int s = 0; s < DSTATE; ++s) {
                float dA = __expf(de * As_[s]);
                h[s] = fmaf(dA, h[s], dx * Bsh[t][s]);
                p[s] *= dA;
                yl = fmaf(h[s], Csh[t][s], yl);
            }
            xms[g] = f2bf(yl);
        }
#pragma unroll
        for (int s = 0; s < DSTATE; ++s) {
            size_t o = ((size_t)(b * NC + c) * DSTATE + s) * 1024 + d;
            P[o] = f2bf(p[s]);
            S[o] = f2bf(h[s]);
        }
    }
}

// ---------------------------------------------------------------------------
// Pass 2 (R10): serial combine over NC=64 chunks, 8-deep batched, Hinit over P.
// ---------------------------------------------------------------------------
__global__ __launch_bounds__(256)
void scan_pass2(const bf16* P, const bf16* __restrict__ S, bf16* Hinit, int NC)
{
    int g = blockIdx.x * 256 + threadIdx.x;
    int d = g & 1023;
    int s = (g >> 10) & 15;
    int b = g >> 14;
    const size_t cs = (size_t)DSTATE * 1024;
    size_t o = ((size_t)(b * NC) * DSTATE + s) * 1024 + d;
    float h = 0.f;
    for (int c0 = 0; c0 < NC; c0 += 8) {
        float pv[8], sv[8];
#pragma unroll
        for (int j = 0; j < 8; ++j) {
            pv[j] = bf2f(P[o + j * cs]);
            sv[j] = bf2f(S[o + j * cs]);
        }
#pragma unroll
        for (int j = 0; j < 8; ++j) {
            Hinit[o + j * cs] = f2bf(h);
            h = fmaf(pv[j], h, sv[j]);
        }
        o += 8 * cs;
    }
}

// ---------------------------------------------------------------------------
// Pass 3 (R10, correction-only): dY holds delta in, y*z out (same buffer).
// y_t = ylocal_t + sum_s C_t[s]*w_t[s]; w updated multiplicatively.
// ---------------------------------------------------------------------------
__global__ __launch_bounds__(256)
void scan_pass3(bf16* dY, const bf16* __restrict__ ylocal,
                const bf16* __restrict__ dblb, const float* __restrict__ A_log,
                const bf16* __restrict__ Hinit,
                const bf16* __restrict__ zs, int L)
{
    const int NC = L / CHUNK;
    const int c = blockIdx.x % NC;
    const int b = blockIdx.x / NC;
    const int d = blockIdx.y * 256 + threadIdx.x;

    __shared__ float Csh[CHUNK][DSTATE];
#pragma unroll
    for (int it = 0; it < CHUNK * DSTATE / 256; ++it) {
        int idx = threadIdx.x + it * 256;
        int t = idx >> 4, s = idx & 15;
        Csh[t][s] = bf2f(dblb[(size_t)(b * L + c * CHUNK + t) * 64 + 48 + s]);
    }
    __syncthreads();

    float As_[DSTATE];
    const bool fastA = load_A(A_log, d, As_);

    float w[DSTATE];
#pragma unroll
    for (int s = 0; s < DSTATE; ++s)
        w[s] = bf2f(Hinit[((size_t)(b * NC + c) * DSTATE + s) * 1024 + d]);

    const size_t rb = (size_t)(b * L + c * CHUNK);

    if (fastA) {
        for (int t = 0; t < CHUNK; ++t) {
            size_t g = (rb + t) * 1024 + d;
            float de = bf2f(dY[g]);
            float yl = bf2f(ylocal[g]);
            float z  = bf2f(zs[g]);
            float r = __expf(-de);
            float a[DSTATE];
            powa(r, a);
            float c0 = 0.f, c1 = 0.f, c2 = 0.f, c3 = 0.f;
#pragma unroll
            for (int s = 0; s < DSTATE; s += 4) {
                w[s] *= a[s];
                c0 = fmaf(w[s], Csh[t][s], c0);
                w[s+1] *= a[s+1];
                c1 = fmaf(w[s+1], Csh[t][s+1], c1);
                w[s+2] *= a[s+2];
                c2 = fmaf(w[s+2], Csh[t][s+2], c2);
                w[s+3] *= a[s+3];
                c3 = fmaf(w[s+3], Csh[t][s+3], c3);
            }
            dY[g] = f2bf((yl + (c0 + c1) + (c2 + c3)) * z);
        }
    } else {
        for (int t = 0; t < CHUNK; ++t) {
            size_t g = (rb + t) * 1024 + d;
            float de = bf2f(dY[g]);
            float yl = bf2f(ylocal[g]);
            float z  = bf2f(zs[g]);
            float c0 = 0.f, c1 = 0.f;
#pragma unroll
            for (int s = 0; s < DSTATE; s += 2) {
                w[s]   *= __expf(de * As_[s]);
                c0 = fmaf(w[s], Csh[t][s], c0);
                w[s+1] *= __expf(de * As_[s+1]);
                c1 = fmaf(w[s+1], Csh[t][s+1], c1);
            }
            dY[g] = f2bf((yl + c0 + c1) * z);
        }
    }
}

// ---------------------------------------------------------------------------

extern "C" void kernel_launch(void* const* d_in, const int* in_sizes, int n_in,
                              void* d_out, int out_size, void* d_ws, size_t ws_size,
                              hipStream_t stream)
{
    (void)in_sizes; (void)n_in; (void)out_size;

    const float* x         = (const float*)d_in[0];
    const float* enc_w1    = (const float*)d_in[1];
    const float* enc_b1    = (const float*)d_in[2];
    const float* enc_w2    = (const float*)d_in[3];
    const float* enc_b2    = (const float*)d_in[4];
    const float* in_proj_w = (const float*)d_in[5];
    const float* conv_w    = (const float*)d_in[6];
    const float* conv_b    = (const float*)d_in[7];
    const float* x_proj_w  = (const float*)d_in[8];
    const float* dt_proj_w = (const float*)d_in[9];
    const float* dt_proj_b = (const float*)d_in[10];
    const float* A_log     = (const float*)d_in[11];
    const float* D_param   = (const float*)d_in[12];
    const float* out_proj_w= (const float*)d_in[13];
    const float* dec_w1    = (const float*)d_in[14];
    const float* dec_b1    = (const float*)d_in[15];
    const float* dec_w2    = (const float*)d_in[16];
    const float* dec_b2    = (const float*)d_in[17];
    float* out = (float*)d_out;

    const int L = 2048, NC = L / CHUNK;   // NC = 64

    // ---- bf16 fixed region (weights + x) ----
    bf16* wb = (bf16*)d_ws;
    size_t off = 0;
    bf16* w_enc1 = wb + off; off += 16384;
    bf16* w_enc2 = wb + off; off += 131072;
    bf16* w_inpj = wb + off; off += 1048576;
    bf16* w_xprj = wb + off; off += 65536;
    bf16* w_dtpj = wb + off; off += 32768;
    bf16* w_outp = wb + off; off += 524288;
    bf16* w_dec1 = wb + off; off += 131072;
    bf16* w_dec2 = wb + off; off += 16384;
    bf16* xbf    = wb + off; off += 1048576;
    const size_t fixedB = off * 2;         // 6,029,312 B

    // per-row bytes: hbf(512)+ubf(1024)+slot3(2048)+zbf(2048)+xms(2048)
    //               +dblb(128)+Pb(1024)+Sb(1024) = 9856  (R10 layout)
    const size_t PER_ROW = 9856;
    int SPLIT = 8;
    if      (fixedB + (size_t)16384 * PER_ROW <= ws_size) SPLIT = 1;  // 167.5 MB
    else if (fixedB + (size_t) 8192 * PER_ROW <= ws_size) SPLIT = 2;
    else if (fixedB + (size_t) 4096 * PER_ROW <= ws_size) SPLIT = 4;

    const int NB = 8 / SPLIT;
    const int MR = NB * L;

    char* pb = (char*)d_ws + fixedB;
    bf16* hbf   = (bf16*)pb;                     // MR x 256
    bf16* ubf   = hbf   + (size_t)MR * 256;      // MR x 512 (u, o)
    bf16* slot3 = ubf   + (size_t)MR * 512;      // MR x 1024 (xm_raw -> delta -> y)
    bf16* zbf   = slot3 + (size_t)MR * 1024;     // MR x 1024 (silu'd z)
    bf16* xms   = zbf   + (size_t)MR * 1024;     // MR x 1024 (xm_silu -> ylocal)
    bf16* dblb  = xms   + (size_t)MR * 1024;     // MR x 64
    bf16* Pb    = dblb  + (size_t)MR * 64;       // MR x 512 bf16 (-> Hinit)
    bf16* Sb    = Pb    + (size_t)MR * 512;      // MR x 512 bf16

    CastJobs J;
    J.src[0] = enc_w1;     J.dst[0] = w_enc1; J.n[0] = 16384;
    J.src[1] = enc_w2;     J.dst[1] = w_enc2; J.n[1] = 131072;
    J.src[2] = in_proj_w;  J.dst[2] = w_inpj; J.n[2] = 1048576;
    J.src[3] = x_proj_w;   J.dst[3] = w_xprj; J.n[3] = 65536;
    J.src[4] = dt_proj_w;  J.dst[4] = w_dtpj; J.n[4] = 32768;
    J.src[5] = out_proj_w; J.dst[5] = w_outp; J.n[5] = 524288;
    J.src[6] = dec_w1;     J.dst[6] = w_dec1; J.n[6] = 131072;
    J.src[7] = dec_w2;     J.dst[7] = w_dec2; J.n[7] = 16384;
    J.src[8] = x;          J.dst[8] = xbf;    J.n[8] = 1048576;
    cast_bf16_kernel<<<dim3(128, 9), 256, 0, stream>>>(J);

    dim3 blk(256);
    for (int p = 0; p < SPLIT; ++p) {
        const bf16* xp  = xbf + (size_t)p * MR * 64;
        float*     outp = out + (size_t)p * MR * 64;

        // enc1: relu(x @ enc_w1^T + b1) -> h (MR x 256), K=64
        gemm_mfma<64,128,1,1,0,0><<<dim3(2, MR/64), blk, 0, stream>>>(
            xp, 64, w_enc1, 64, enc_b1, hbf, nullptr, 0, 256, 64);
        // enc2: u = h @ enc_w2^T + b2 (MR x 512), K=256
        gemm_mfma<128,128,0,1,0,0><<<dim3(4, MR/128), blk, 0, stream>>>(
            hbf, 256, w_enc2, 256, enc_b2, ubf, nullptr, 0, 512, 256);
        // in_proj FUSED (N=2048): cols<1024 -> slot3 (raw), cols>=1024 -> zbf (silu)
        gemm_mfma<128,128,0,1,1,3><<<dim3(16, MR/128), blk, 0, stream>>>(
            ubf, 512, w_inpj, 512, nullptr, slot3, zbf, 1024, 1024, 512);
        // conv + silu: slot3 -> xms
        conv_silu_kernel<<<dim3(NB * (L/32), 4), blk, 0, stream>>>(
            slot3, conv_w, conv_b, xms, L);
        // x_proj: dbl = xms @ x_proj_w^T (MR x 64), K=1024
        gemm_mfma<64,64,0,1,0,0><<<dim3(1, MR/64), blk, 0, stream>>>(
            xms, 1024, w_xprj, 1024, nullptr, dblb, nullptr, 0, 64, 1024);
        // scan pass1 (+ fused dt_proj/softplus): delta -> slot3, ylocal -> xms
        scan_pass1<<<dim3(NB * NC, 4), blk, 0, stream>>>(
            slot3, xms, dblb, w_dtpj, dt_proj_b, A_log, D_param, Pb, Sb, L);
        scan_pass2<<<dim3(NB * 64), blk, 0, stream>>>(Pb, Sb, Pb, NC);
        // pass3: correction-only; delta->y in place over slot3
        scan_pass3<<<dim3(NB * NC, 4), blk, 0, stream>>>(
            slot3, xms, dblb, A_log, Pb, zbf, L);
        // out_proj: o = y @ out_proj_w^T (MR x 512), K=1024
        gemm_mfma<128,128,0,1,0,0><<<dim3(4, MR/128), blk, 0, stream>>>(
            slot3, 1024, w_outp, 1024, nullptr, ubf, nullptr, 0, 512, 1024);
        // dec1: relu(o @ dec_w1^T + b1) (MR x 256), K=512
        gemm_mfma<64,128,1,1,0,0><<<dim3(2, MR/64), blk, 0, stream>>>(
            ubf, 512, w_dec1, 512, dec_b1, hbf, nullptr, 0, 256, 512);
        // dec2: out = h2 @ dec_w2^T + b2 (MR x 64 f32), K=256
        gemm_mfma<64,64,0,0,0,0><<<dim3(1, MR/64), blk, 0, stream>>>(
            hbf, 256, w_dec2, 256, dec_b2, outp, nullptr, 0, 64, 256);
    }
}